// Round 11
// baseline (165.817 us; speedup 1.0000x reference)
//
#include <hip/hip_runtime.h>

// LightGCN layer: out[d] = in_deg[d]^-1/2 * sum_{e:dst[e]=d} x[src[e]] * out_deg[src[e]]^-1/2
//
// Round 11: round-10 fusions kept, EPB reverted to 4096 (round-10's 3072
// regressed: partition cost is per-block fixed work, not occupancy).
// NEW: src-side multisplit deleted — out-degree needs counting, not grouping.
// Non-returning atomicAdd(&out_cnt[src],1) in partition pass 1 (fire-and-
// forget; round-4's cost was the *returning* cursor atomic chain). Kills
// pbuf_s (1.6 MB write + read), half of partition's LDS work, bincnt's src
// pass. out_cnt is final at the kernel boundary -> bincnt converts x with it.

#define D_FEAT 96
#define CAP 64
#define PART_SHIFT 8
#define PNODES 256
#define NP_MAX 256
#define EPB 4096
#define OVF_CAP 8192

__device__ __forceinline__ unsigned short f2bf_rne(float f) {
    unsigned u = __float_as_uint(f);
    unsigned r = (u >> 16) & 1u;
    u += 0x7fffu + r;
    return (unsigned short)(u >> 16);
}

// ---------------- pass 1: dst-partition + src count ----------------

__global__ __launch_bounds__(256) void partition_kernel(
        const int* __restrict__ src, const int* __restrict__ dst,
        int n_edges, int np, int stride,
        int* __restrict__ pcur_d, int* __restrict__ out_cnt,
        unsigned* __restrict__ pbuf_d,
        int* __restrict__ ctr,            // [0]=ovf_n [1]=povf_n
        int* __restrict__ povf_d) {
    __shared__ int hcd[NP_MAX];
    __shared__ int bd[NP_MAX];
    __shared__ int od[NP_MAX];
    const int base = blockIdx.x * EPB;

    for (int i = threadIdx.x; i < NP_MAX; i += 256) { hcd[i] = 0; od[i] = 0; }
    __syncthreads();

    unsigned v[16];
    #pragma unroll
    for (int k = 0; k < 16; ++k) {
        int i = base + (int)threadIdx.x + (k << 8);
        if (i < n_edges) {
            int s = src[i], d = dst[i];
            unsigned pv = (unsigned)d | ((unsigned)s << 16);
            v[k] = pv;
            atomicAdd(&hcd[d >> PART_SHIFT], 1);
            atomicAdd(&out_cnt[s], 1);        // non-returning, fire-and-forget
        }
    }
    __syncthreads();

    for (int p = threadIdx.x; p < np; p += 256) {
        int cd = hcd[p];
        bd[p] = cd ? atomicAdd(&pcur_d[p], cd) : 0;
    }
    __syncthreads();

    #pragma unroll
    for (int k = 0; k < 16; ++k) {
        int i = base + (int)threadIdx.x + (k << 8);
        if (i < n_edges) {
            unsigned pv = v[k];
            int d = (int)(pv & 0xffffu);
            int pd = d >> PART_SHIFT;
            int j = bd[pd] + atomicAdd(&od[pd], 1);
            if (j < stride) pbuf_d[(size_t)pd * stride + j] = pv;
            else { int k2 = atomicAdd(&ctr[1], 1); if (k2 < OVF_CAP) povf_d[k2] = (int)pv; }
        }
    }
}

// ---------------- pass 2: bin dst + convert (fused) ----------------
// out_cnt is final (partition kernel completed) -> convert x rows here.

__global__ __launch_bounds__(256) void bincnt_kernel(
        const unsigned* __restrict__ pbuf_d, const int* __restrict__ pcur_d,
        int stride, int n_nodes,
        const float* __restrict__ x, unsigned* __restrict__ xs,
        const int* __restrict__ out_cnt,
        int* __restrict__ cursor,
        unsigned short* __restrict__ slots,
        int* __restrict__ ctr, int* __restrict__ ovf_d) {
    __shared__ unsigned short lslots[PNODES * CAP];   // 32 KB
    __shared__ int lcnt[PNODES];
    __shared__ int lout[PNODES];
    const int b = blockIdx.x;
    const int nbase = b << PART_SHIFT;
    const int nloc = min(PNODES, n_nodes - nbase);

    for (int i = threadIdx.x; i < PNODES; i += 256) lcnt[i] = 0;
    for (int i = threadIdx.x; i < nloc; i += 256) lout[i] = out_cnt[nbase + i];
    __syncthreads();

    int n = pcur_d[b]; if (n > stride) n = stride;
    for (int i = threadIdx.x; i < n; i += 256) {
        unsigned pv = pbuf_d[(size_t)b * stride + i];
        int dl = (int)(pv & 0xffu);        // d - nbase (partition is 256-aligned)
        int s  = (int)(pv >> 16);
        int pos = atomicAdd(&lcnt[dl], 1);
        if (pos < CAP) lslots[dl * CAP + pos] = (unsigned short)s;
        else { int k = atomicAdd(&ctr[0], 1); if (k < OVF_CAP) ovf_d[k] = (int)pv; }
    }
    __syncthreads();

    for (int i = threadIdx.x; i < nloc; i += 256) cursor[nbase + i] = lcnt[i];
    // slot tile write-out (coalesced)
    const unsigned* ls = (const unsigned*)lslots;
    unsigned* gs = (unsigned*)slots + (size_t)nbase * (CAP / 2);
    const int ncopy = nloc * (CAP / 2);
    for (int i = threadIdx.x; i < ncopy; i += 256) gs[i] = ls[i];

    // convert this block's x rows -> pre-scaled bf16 xs
    const int ntot = nloc * 48;
    for (int i = threadIdx.x; i < ntot; i += 256) {
        int nd = i / 48;
        int j  = i - nd * 48;
        int c  = lout[nd];
        float w = rsqrtf((float)(c < 1 ? 1 : c));
        float2 vv = *(const float2*)(x + (size_t)(nbase + nd) * D_FEAT + j * 2);
        unsigned lo = f2bf_rne(vv.x * w);
        unsigned hi = f2bf_rne(vv.y * w);
        xs[(size_t)(nbase + nd) * 48 + j] = lo | (hi << 16);
    }
}

// Exactness fixup for (statistically impossible) partition-buffer overflow:
// povf edges join the ovf list and their dst's cursor count.
__global__ void fixup_kernel(int* __restrict__ ctr,
                             const int* __restrict__ povf_d,
                             int* __restrict__ ovf_d,
                             int* __restrict__ cursor) {
    int np_ = ctr[1]; if (np_ > OVF_CAP) np_ = OVF_CAP;
    for (int i = threadIdx.x; i < np_; i += 256) {
        unsigned pv = (unsigned)povf_d[i];
        atomicAdd(&cursor[pv & 0xffffu], 1);
        int k = atomicAdd(&ctr[0], 1);
        if (k < OVF_CAP) ovf_d[k] = (int)pv;
    }
}

// ---------------- gather: wave per node, 16-deep unrolled, self-serve ovf ----

__global__ __launch_bounds__(256) void gather_kernel(
        const unsigned* __restrict__ xs,
        const unsigned short* __restrict__ slots,
        const int* __restrict__ cursor,
        const float* __restrict__ x,
        const int* __restrict__ out_cnt,
        const int* __restrict__ ctr,
        const int* __restrict__ ovf_d,
        float* __restrict__ out, int n_nodes) {
    int wid  = threadIdx.x >> 6;
    int lane = threadIdx.x & 63;
    int node = __builtin_amdgcn_readfirstlane(blockIdx.x * 4 + wid);
    if (node >= n_nodes) return;

    int cnt_all = __builtin_amdgcn_readfirstlane(cursor[node]);
    int cnt = cnt_all < CAP ? cnt_all : CAP;

    float accx = 0.f, accy = 0.f;
    const bool act = lane < 48;        // 48 lanes x (2 bf16) = 96 features

    if (cnt > 0) {
        int idx  = lane < cnt ? lane : cnt - 1;
        int sval = (int)slots[node * CAP + idx];   // lane l holds slot l's src id

        int e = 0;
        for (; e + 16 <= cnt; e += 16) {
            if (act) {
                unsigned u[16];
                #pragma unroll
                for (int k = 0; k < 16; ++k) {
                    int s = __builtin_amdgcn_readlane(sval, e + k);
                    u[k] = xs[s * 48 + lane];
                }
                #pragma unroll
                for (int k = 0; k < 16; ++k) {
                    accx += __uint_as_float(u[k] << 16);
                    accy += __uint_as_float(u[k] & 0xffff0000u);
                }
            }
        }
        for (; e + 4 <= cnt; e += 4) {
            if (act) {
                unsigned u[4];
                #pragma unroll
                for (int k = 0; k < 4; ++k) {
                    int s = __builtin_amdgcn_readlane(sval, e + k);
                    u[k] = xs[s * 48 + lane];
                }
                #pragma unroll
                for (int k = 0; k < 4; ++k) {
                    accx += __uint_as_float(u[k] << 16);
                    accy += __uint_as_float(u[k] & 0xffff0000u);
                }
            }
        }
        for (; e < cnt; ++e) {
            if (act) {
                int s = __builtin_amdgcn_readlane(sval, e);
                unsigned u0 = xs[s * 48 + lane];
                accx += __uint_as_float(u0 << 16);
                accy += __uint_as_float(u0 & 0xffff0000u);
            }
        }
    }

    // self-service overflow: only nodes with in-degree > CAP (normally none)
    if (cnt_all > CAP) {
        int novf = __builtin_amdgcn_readfirstlane(ctr[0]);
        if (novf > OVF_CAP) novf = OVF_CAP;
        for (int k = 0; k < novf; ++k) {
            unsigned pv = (unsigned)ovf_d[k];
            if ((int)(pv & 0xffffu) == node) {
                int s = (int)(pv >> 16);
                int c = out_cnt[s];
                float w = rsqrtf((float)(c < 1 ? 1 : c));
                if (act) {
                    accx += w * x[(size_t)s * D_FEAT + lane * 2];
                    accy += w * x[(size_t)s * D_FEAT + lane * 2 + 1];
                }
            }
        }
    }

    float sc = rsqrtf((float)(cnt_all < 1 ? 1 : cnt_all));
    if (act) {
        float* op = out + (size_t)node * D_FEAT + lane * 2;
        op[0] = accx * sc;
        op[1] = accy * sc;
    }
}

// ---------------- fallback (round-1 atomic scatter, any size) ----------------

__global__ void degree_kernel(const int* __restrict__ src,
                              const int* __restrict__ dst,
                              int* __restrict__ out_cnt,
                              int* __restrict__ in_cnt, int n_edges) {
    int i = blockIdx.x * blockDim.x + threadIdx.x;
    if (i < n_edges) {
        atomicAdd(&out_cnt[src[i]], 1);
        atomicAdd(&in_cnt[dst[i]], 1);
    }
}

__global__ void scale_kernel(float* __restrict__ osc, float* __restrict__ isc, int n) {
    int i = blockIdx.x * blockDim.x + threadIdx.x;
    if (i < n) {
        int c0 = ((const int*)osc)[i];
        int c1 = ((const int*)isc)[i];
        osc[i] = rsqrtf((float)(c0 < 1 ? 1 : c0));
        isc[i] = rsqrtf((float)(c1 < 1 ? 1 : c1));
    }
}

__global__ void scatter_kernel(const float* __restrict__ x,
                               const int* __restrict__ src,
                               const int* __restrict__ dst,
                               const float* __restrict__ osc,
                               const float* __restrict__ isc,
                               float* __restrict__ out, int n_edges) {
    int idx = blockIdx.x * blockDim.x + threadIdx.x;
    int e = idx / 24, c = idx % 24;
    if (e >= n_edges) return;
    int s = src[e], d = dst[e];
    float w = osc[s] * isc[d];
    const float4 v = *(const float4*)(x + (size_t)s * D_FEAT + c * 4);
    float* o = out + (size_t)d * D_FEAT + c * 4;
    unsafeAtomicAdd(o + 0, v.x * w);
    unsafeAtomicAdd(o + 1, v.y * w);
    unsafeAtomicAdd(o + 2, v.z * w);
    unsafeAtomicAdd(o + 3, v.w * w);
}

// ---------------- launcher ----------------

extern "C" void kernel_launch(void* const* d_in, const int* in_sizes, int n_in,
                              void* d_out, int out_size, void* d_ws, size_t ws_size,
                              hipStream_t stream) {
    const float* x  = (const float*)d_in[0];
    const int* src  = (const int*)d_in[1];
    const int* dst  = (const int*)d_in[2];
    float* out      = (float*)d_out;

    const int n_edges = in_sizes[1];
    const int n_nodes = in_sizes[0] / D_FEAT;

    const int np = (n_nodes + PNODES - 1) / PNODES;
    const int avg = n_edges / (np > 0 ? np : 1);
    const int stride = avg + avg / 4 + 1024;

    const size_t pbuf_words = (size_t)np * stride;           // dst buffer (uint)

    // ws layout (int32 units). First 512+65536 ints are zeroed each call:
    int* pcur_d  = (int*)d_ws;            // 256
    int* ctr     = pcur_d + 256;          // 2 (pad to 512)
    int* out_cnt = pcur_d + 512;          // 65536
    int* ovf_d   = out_cnt + 65536;       // OVF_CAP (packed v)
    int* povf_d  = ovf_d + OVF_CAP;       // OVF_CAP
    int* cursor  = povf_d + OVF_CAP;      // 65536
    unsigned* pbuf_dst = (unsigned*)(cursor + 65536);
    unsigned* xs = pbuf_dst + pbuf_words;
    unsigned short* slots = (unsigned short*)(xs + (size_t)n_nodes * 48);

    const size_t needed = ((size_t)512 + 2 * 65536 + 2 * OVF_CAP + pbuf_words +
                           (size_t)n_nodes * 48 + (size_t)n_nodes * (CAP / 2)) * 4;

    if (ws_size >= needed && n_nodes <= 65536 && np <= NP_MAX) {
        // zero pcur_d, ctr, out_cnt in one contiguous memset
        (void)hipMemsetAsync(d_ws, 0, (512 + 65536) * sizeof(int), stream);

        partition_kernel<<<(n_edges + EPB - 1) / EPB, 256, 0, stream>>>(
            src, dst, n_edges, np, stride, pcur_d, out_cnt,
            pbuf_dst, ctr, povf_d);

        bincnt_kernel<<<np, 256, 0, stream>>>(
            pbuf_dst, pcur_d, stride, n_nodes,
            x, xs, out_cnt, cursor, slots, ctr, ovf_d);

        fixup_kernel<<<1, 256, 0, stream>>>(ctr, povf_d, ovf_d, cursor);

        gather_kernel<<<(n_nodes + 3) / 4, 256, 0, stream>>>(
            xs, slots, cursor, x, out_cnt, ctr, ovf_d, out, n_nodes);
    } else {
        // fallback: atomic scatter (round-1 path, any size)
        float* osc = (float*)d_ws;
        float* isc = osc + 65536;
        (void)hipMemsetAsync(d_ws, 0, 2 * 65536 * sizeof(int), stream);
        (void)hipMemsetAsync(d_out, 0, (size_t)out_size * sizeof(float), stream);
        degree_kernel<<<(n_edges + 255) / 256, 256, 0, stream>>>(
            src, dst, (int*)osc, (int*)isc, n_edges);
        scale_kernel<<<(n_nodes + 255) / 256, 256, 0, stream>>>(osc, isc, n_nodes);
        const int total = n_edges * 24;
        scatter_kernel<<<(total + 255) / 256, 256, 0, stream>>>(
            x, src, dst, osc, isc, out, n_edges);
    }
}

// Round 12
// 138.171 us; speedup vs baseline: 1.2001x; 1.2001x over previous
//
#include <hip/hip_runtime.h>

// LightGCN layer: out[d] = in_deg[d]^-1/2 * sum_{e:dst[e]=d} x[src[e]] * out_deg[src[e]]^-1/2
//
// Round 12: R9 base (best, 141.7) with:
//  - EPB 3328 -> 241 partition blocks (<=256 CUs; R10's 261-block grid tail
//    was its regression, not the fusions).
//  - convert fused into bincnt.
//  - fixup folded into bincnt: each block integrates povf/sovf entries for its
//    own node range through the normal LDS bin/count path (also fixes the
//    latent povf-undercount inconsistency in R9-R11).
//  - overflow self-served in gather (slots-full <=> cnt_all>CAP now exact).
//  4 dispatches total (memset + 3 kernels), was 7.
// Gather is at its line-rate floor (53 G lines/s measured across R2/R4):
// 3 cache lines per 192 B bf16 row is minimal -> ~44 us; untouched.

#define D_FEAT 96
#define CAP 64
#define PART_SHIFT 8
#define PNODES 256
#define NP_MAX 256
#define EPB 3328            // 13 * 256; 800k edges -> 241 blocks (<= 256 CUs)
#define EREG 13
#define OVF_CAP 8192

__device__ __forceinline__ unsigned short f2bf_rne(float f) {
    unsigned u = __float_as_uint(f);
    unsigned r = (u >> 16) & 1u;
    u += 0x7fffu + r;
    return (unsigned short)(u >> 16);
}

// ---------------- pass 1: dual-side multisplit partition ----------------

__global__ __launch_bounds__(256) void partition_kernel(
        const int* __restrict__ src, const int* __restrict__ dst,
        int n_edges, int np, int stride,
        int* __restrict__ pcur_d, int* __restrict__ pcur_s,
        unsigned* __restrict__ pbuf_d, unsigned short* __restrict__ pbuf_s,
        int* __restrict__ ctr,            // [0]=ovf_n [1]=povf_n [2]=sovf_n
        int* __restrict__ povf_d, int* __restrict__ sovf_d) {
    __shared__ int hcd[NP_MAX], hcs[NP_MAX];
    __shared__ int bd[NP_MAX], bs_[NP_MAX];
    __shared__ int od[NP_MAX], os_[NP_MAX];
    const int base = blockIdx.x * EPB;

    for (int i = threadIdx.x; i < NP_MAX; i += 256) {
        hcd[i] = 0; hcs[i] = 0; od[i] = 0; os_[i] = 0;
    }
    __syncthreads();

    unsigned v[EREG];
    #pragma unroll
    for (int k = 0; k < EREG; ++k) {
        int i = base + (int)threadIdx.x + (k << 8);
        if (i < n_edges) {
            int s = src[i], d = dst[i];
            unsigned pv = (unsigned)d | ((unsigned)s << 16);
            v[k] = pv;
            atomicAdd(&hcd[d >> PART_SHIFT], 1);
            atomicAdd(&hcs[s >> PART_SHIFT], 1);
        }
    }
    __syncthreads();

    for (int p = threadIdx.x; p < np; p += 256) {
        int cd = hcd[p];
        bd[p] = cd ? atomicAdd(&pcur_d[p], cd) : 0;
        int cs = hcs[p];
        bs_[p] = cs ? atomicAdd(&pcur_s[p], cs) : 0;
    }
    __syncthreads();

    #pragma unroll
    for (int k = 0; k < EREG; ++k) {
        int i = base + (int)threadIdx.x + (k << 8);
        if (i < n_edges) {
            unsigned pv = v[k];
            int d = (int)(pv & 0xffffu);
            int s = (int)(pv >> 16);
            int pd = d >> PART_SHIFT;
            int j = bd[pd] + atomicAdd(&od[pd], 1);
            if (j < stride) pbuf_d[(size_t)pd * stride + j] = pv;
            else { int k2 = atomicAdd(&ctr[1], 1); if (k2 < OVF_CAP) povf_d[k2] = (int)pv; }
            int ps = s >> PART_SHIFT;
            int j2 = bs_[ps] + atomicAdd(&os_[ps], 1);
            if (j2 < stride) pbuf_s[(size_t)ps * stride + j2] = (unsigned short)s;
            else { int k3 = atomicAdd(&ctr[2], 1); if (k3 < OVF_CAP) sovf_d[k3] = s; }
        }
    }
}

// ---- pass 2: bin dst + count src + integrate povf/sovf + convert (fused) ----

__global__ __launch_bounds__(256) void bincnt_kernel(
        const unsigned* __restrict__ pbuf_d, const int* __restrict__ pcur_d,
        const unsigned short* __restrict__ pbuf_s, const int* __restrict__ pcur_s,
        int stride, int n_nodes,
        const float* __restrict__ x, unsigned* __restrict__ xs,
        int* __restrict__ cursor, int* __restrict__ out_cnt,
        unsigned short* __restrict__ slots,
        int* __restrict__ ctr,
        const int* __restrict__ povf_d, const int* __restrict__ sovf_d,
        int* __restrict__ ovf_d) {
    __shared__ unsigned short lslots[PNODES * CAP];   // 32 KB
    __shared__ int lcnt[PNODES];
    __shared__ int lout[PNODES];
    const int b = blockIdx.x;
    const int nbase = b << PART_SHIFT;
    const int nloc = min(PNODES, n_nodes - nbase);

    for (int i = threadIdx.x; i < PNODES; i += 256) { lcnt[i] = 0; lout[i] = 0; }
    __syncthreads();

    // dst side: bin into slots
    int n = pcur_d[b]; if (n > stride) n = stride;
    for (int i = threadIdx.x; i < n; i += 256) {
        unsigned pv = pbuf_d[(size_t)b * stride + i];
        int dl = (int)(pv & 0xffu);        // d - nbase (partition is 256-aligned)
        int s  = (int)(pv >> 16);
        int pos = atomicAdd(&lcnt[dl], 1);
        if (pos < CAP) lslots[dl * CAP + pos] = (unsigned short)s;
        else { int k = atomicAdd(&ctr[0], 1); if (k < OVF_CAP) ovf_d[k] = (int)pv; }
    }
    // src side: histogram out-degree
    int n2 = pcur_s[b]; if (n2 > stride) n2 = stride;
    for (int i = threadIdx.x; i < n2; i += 256) {
        int s = (int)pbuf_s[(size_t)b * stride + i];
        atomicAdd(&lout[s & (PNODES - 1)], 1);
    }
    // integrate partition-buffer overflow entries for THIS node range
    // (ctr[1]/ctr[2] are normally 0 -> these loops never run)
    int npv = ctr[1];
    if (npv > 0) {
        if (npv > OVF_CAP) npv = OVF_CAP;
        for (int i = threadIdx.x; i < npv; i += 256) {
            unsigned pv = (unsigned)povf_d[i];
            int d = (int)(pv & 0xffffu);
            if ((d >> PART_SHIFT) == b) {
                int dl = d & (PNODES - 1);
                int pos = atomicAdd(&lcnt[dl], 1);
                if (pos < CAP) lslots[dl * CAP + pos] = (unsigned short)(pv >> 16);
                else { int k = atomicAdd(&ctr[0], 1); if (k < OVF_CAP) ovf_d[k] = (int)pv; }
            }
        }
    }
    int nsv = ctr[2];
    if (nsv > 0) {
        if (nsv > OVF_CAP) nsv = OVF_CAP;
        for (int i = threadIdx.x; i < nsv; i += 256) {
            int s = sovf_d[i];
            if ((s >> PART_SHIFT) == b) atomicAdd(&lout[s & (PNODES - 1)], 1);
        }
    }
    __syncthreads();

    for (int i = threadIdx.x; i < nloc; i += 256) {
        cursor[nbase + i]  = lcnt[i];
        out_cnt[nbase + i] = lout[i];
    }
    // slot tile write-out (coalesced)
    const unsigned* ls = (const unsigned*)lslots;
    unsigned* gs = (unsigned*)slots + (size_t)nbase * (CAP / 2);
    const int ncopy = nloc * (CAP / 2);
    for (int i = threadIdx.x; i < ncopy; i += 256) gs[i] = ls[i];

    // convert this block's x rows -> pre-scaled bf16 xs (float4 granular)
    const int ntot = nloc * 24;                 // 24 float4 per 96-feat row
    for (int i = threadIdx.x; i < ntot; i += 256) {
        int nd = i / 24;
        int j  = i - nd * 24;
        int c  = lout[nd];
        float w = rsqrtf((float)(c < 1 ? 1 : c));
        float4 vv = ((const float4*)(x + (size_t)(nbase + nd) * D_FEAT))[j];
        unsigned lo0 = f2bf_rne(vv.x * w), hi0 = f2bf_rne(vv.y * w);
        unsigned lo1 = f2bf_rne(vv.z * w), hi1 = f2bf_rne(vv.w * w);
        uint2 o;
        o.x = lo0 | (hi0 << 16);
        o.y = lo1 | (hi1 << 16);
        ((uint2*)(xs + (size_t)(nbase + nd) * 48))[j] = o;
    }
}

// ---------------- gather: wave per node, 16-deep unrolled, self-serve ovf ----

__global__ __launch_bounds__(256) void gather_kernel(
        const unsigned* __restrict__ xs,
        const unsigned short* __restrict__ slots,
        const int* __restrict__ cursor,
        const float* __restrict__ x,
        const int* __restrict__ out_cnt,
        const int* __restrict__ ctr,
        const int* __restrict__ ovf_d,
        float* __restrict__ out, int n_nodes) {
    int wid  = threadIdx.x >> 6;
    int lane = threadIdx.x & 63;
    int node = __builtin_amdgcn_readfirstlane(blockIdx.x * 4 + wid);
    if (node >= n_nodes) return;

    int cnt_all = __builtin_amdgcn_readfirstlane(cursor[node]);
    int cnt = cnt_all < CAP ? cnt_all : CAP;

    float accx = 0.f, accy = 0.f;
    const bool act = lane < 48;        // 48 lanes x (2 bf16) = 96 features

    if (cnt > 0) {
        int idx  = lane < cnt ? lane : cnt - 1;
        int sval = (int)slots[node * CAP + idx];   // lane l holds slot l's src id

        int e = 0;
        for (; e + 16 <= cnt; e += 16) {
            if (act) {
                unsigned u[16];
                #pragma unroll
                for (int k = 0; k < 16; ++k) {
                    int s = __builtin_amdgcn_readlane(sval, e + k);
                    u[k] = xs[s * 48 + lane];
                }
                #pragma unroll
                for (int k = 0; k < 16; ++k) {
                    accx += __uint_as_float(u[k] << 16);
                    accy += __uint_as_float(u[k] & 0xffff0000u);
                }
            }
        }
        for (; e + 4 <= cnt; e += 4) {
            if (act) {
                unsigned u[4];
                #pragma unroll
                for (int k = 0; k < 4; ++k) {
                    int s = __builtin_amdgcn_readlane(sval, e + k);
                    u[k] = xs[s * 48 + lane];
                }
                #pragma unroll
                for (int k = 0; k < 4; ++k) {
                    accx += __uint_as_float(u[k] << 16);
                    accy += __uint_as_float(u[k] & 0xffff0000u);
                }
            }
        }
        for (; e < cnt; ++e) {
            if (act) {
                int s = __builtin_amdgcn_readlane(sval, e);
                unsigned u0 = xs[s * 48 + lane];
                accx += __uint_as_float(u0 << 16);
                accy += __uint_as_float(u0 & 0xffff0000u);
            }
        }
    }

    // self-service overflow: only nodes with in-degree > CAP (normally none).
    // Consistent: slots overflow <=> cnt_all > CAP (povf edges binned by bincnt).
    if (cnt_all > CAP) {
        int novf = __builtin_amdgcn_readfirstlane(ctr[0]);
        if (novf > OVF_CAP) novf = OVF_CAP;
        for (int k = 0; k < novf; ++k) {
            unsigned pv = (unsigned)ovf_d[k];
            if ((int)(pv & 0xffffu) == node) {
                int s = (int)(pv >> 16);
                int c = out_cnt[s];
                float w = rsqrtf((float)(c < 1 ? 1 : c));
                if (act) {
                    accx += w * x[(size_t)s * D_FEAT + lane * 2];
                    accy += w * x[(size_t)s * D_FEAT + lane * 2 + 1];
                }
            }
        }
    }

    float sc = rsqrtf((float)(cnt_all < 1 ? 1 : cnt_all));
    if (act) {
        float* op = out + (size_t)node * D_FEAT + lane * 2;
        op[0] = accx * sc;
        op[1] = accy * sc;
    }
}

// ---------------- fallback (round-1 atomic scatter, any size) ----------------

__global__ void degree_kernel(const int* __restrict__ src,
                              const int* __restrict__ dst,
                              int* __restrict__ out_cnt,
                              int* __restrict__ in_cnt, int n_edges) {
    int i = blockIdx.x * blockDim.x + threadIdx.x;
    if (i < n_edges) {
        atomicAdd(&out_cnt[src[i]], 1);
        atomicAdd(&in_cnt[dst[i]], 1);
    }
}

__global__ void scale_kernel(float* __restrict__ osc, float* __restrict__ isc, int n) {
    int i = blockIdx.x * blockDim.x + threadIdx.x;
    if (i < n) {
        int c0 = ((const int*)osc)[i];
        int c1 = ((const int*)isc)[i];
        osc[i] = rsqrtf((float)(c0 < 1 ? 1 : c0));
        isc[i] = rsqrtf((float)(c1 < 1 ? 1 : c1));
    }
}

__global__ void scatter_kernel(const float* __restrict__ x,
                               const int* __restrict__ src,
                               const int* __restrict__ dst,
                               const float* __restrict__ osc,
                               const float* __restrict__ isc,
                               float* __restrict__ out, int n_edges) {
    int idx = blockIdx.x * blockDim.x + threadIdx.x;
    int e = idx / 24, c = idx % 24;
    if (e >= n_edges) return;
    int s = src[e], d = dst[e];
    float w = osc[s] * isc[d];
    const float4 v = *(const float4*)(x + (size_t)s * D_FEAT + c * 4);
    float* o = out + (size_t)d * D_FEAT + c * 4;
    unsafeAtomicAdd(o + 0, v.x * w);
    unsafeAtomicAdd(o + 1, v.y * w);
    unsafeAtomicAdd(o + 2, v.z * w);
    unsafeAtomicAdd(o + 3, v.w * w);
}

// ---------------- launcher ----------------

extern "C" void kernel_launch(void* const* d_in, const int* in_sizes, int n_in,
                              void* d_out, int out_size, void* d_ws, size_t ws_size,
                              hipStream_t stream) {
    const float* x  = (const float*)d_in[0];
    const int* src  = (const int*)d_in[1];
    const int* dst  = (const int*)d_in[2];
    float* out      = (float*)d_out;

    const int n_edges = in_sizes[1];
    const int n_nodes = in_sizes[0] / D_FEAT;

    const int np = (n_nodes + PNODES - 1) / PNODES;
    const int avg = n_edges / (np > 0 ? np : 1);
    const int stride = avg + avg / 4 + 1024;
    const int pblocks = (n_edges + EPB - 1) / EPB;

    const size_t pbuf_words  = (size_t)np * stride;          // dst buffer (uint)
    const size_t pbufs_words = (pbuf_words + 1) / 2;         // src buffer (ushort)

    // ws layout (int32 units). First 1024 ints zeroed each call:
    int* pcur_d  = (int*)d_ws;            // 256
    int* pcur_s  = pcur_d + 256;          // 256
    int* ctr     = pcur_d + 512;          // 3 (pad to 1024)
    int* ovf_d   = pcur_d + 1024;         // OVF_CAP (packed v)
    int* povf_d  = ovf_d + OVF_CAP;       // OVF_CAP
    int* sovf_d  = povf_d + OVF_CAP;      // OVF_CAP
    int* out_cnt = sovf_d + OVF_CAP;      // 65536
    int* cursor  = out_cnt + 65536;       // 65536
    unsigned* pbuf_dst = (unsigned*)(cursor + 65536);
    unsigned short* pbuf_src = (unsigned short*)(pbuf_dst + pbuf_words);
    unsigned* xs = pbuf_dst + pbuf_words + pbufs_words;
    unsigned short* slots = (unsigned short*)(xs + (size_t)n_nodes * 48);

    const size_t needed = ((size_t)1024 + 3 * OVF_CAP + 2 * 65536 + pbuf_words +
                           pbufs_words + (size_t)n_nodes * 48 +
                           (size_t)n_nodes * (CAP / 2)) * 4;

    if (ws_size >= needed && n_nodes <= 65536 && np <= NP_MAX && pblocks <= 256) {
        // zero pcur_d, pcur_s, ctr
        (void)hipMemsetAsync(d_ws, 0, 1024 * sizeof(int), stream);

        partition_kernel<<<pblocks, 256, 0, stream>>>(
            src, dst, n_edges, np, stride, pcur_d, pcur_s,
            pbuf_dst, pbuf_src, ctr, povf_d, sovf_d);

        bincnt_kernel<<<np, 256, 0, stream>>>(
            pbuf_dst, pcur_d, pbuf_src, pcur_s, stride, n_nodes,
            x, xs, cursor, out_cnt, slots, ctr, povf_d, sovf_d, ovf_d);

        gather_kernel<<<(n_nodes + 3) / 4, 256, 0, stream>>>(
            xs, slots, cursor, x, out_cnt, ctr, ovf_d, out, n_nodes);
    } else {
        // fallback: atomic scatter (round-1 path, any size)
        float* osc = (float*)d_ws;
        float* isc = osc + 65536;
        (void)hipMemsetAsync(d_ws, 0, 2 * 65536 * sizeof(int), stream);
        (void)hipMemsetAsync(d_out, 0, (size_t)out_size * sizeof(float), stream);
        degree_kernel<<<(n_edges + 255) / 256, 256, 0, stream>>>(
            src, dst, (int*)osc, (int*)isc, n_edges);
        scale_kernel<<<(n_nodes + 255) / 256, 256, 0, stream>>>(osc, isc, n_nodes);
        const int total = n_edges * 24;
        scatter_kernel<<<(total + 255) / 256, 256, 0, stream>>>(
            x, src, dst, osc, isc, out, n_edges);
    }
}